// Round 15
// baseline (644.341 us; speedup 1.0000x reference)
//
#include <hip/hip_runtime.h>
#include <hip/hip_bf16.h>
#include <hip/hip_cooperative_groups.h>
#include <stdint.h>

namespace cg = cooperative_groups;

#define N_ROWS 262144
#define FEAT 1024
#define N_CORES 4096
#define HDIM 1024
#define BN_EPS 1e-5f

typedef __attribute__((ext_vector_type(8))) short bf16x8;
typedef __attribute__((ext_vector_type(4))) float f32x4;

__device__ __forceinline__ unsigned short f2bf(float f) {
  __hip_bfloat16 h = __float2bfloat16(f);
  return __builtin_bit_cast(unsigned short, h);
}

// async global->LDS, 16B per lane, dest = wave-uniform base + lane*16
__device__ __forceinline__ void gll16(const unsigned short* g, unsigned short* l) {
  __builtin_amdgcn_global_load_lds(
      (const __attribute__((address_space(1))) void*)g,
      (__attribute__((address_space(3))) void*)l, 16, 0, 0);
}

// --------------- PREP mega-kernel: segsum | weight transpose | stats/out init
__global__ __launch_bounds__(256)
void k_prep(const float* __restrict__ x, const int* __restrict__ corelen,
            unsigned short* __restrict__ aggb,
            const float* __restrict__ W1, const float* __restrict__ W2,
            const float* __restrict__ W3, unsigned short* __restrict__ Wt,
            float* __restrict__ stats, float* __restrict__ out,
            const float* __restrict__ b4) {
  const int bid = blockIdx.x;
  const int t = threadIdx.x;
  if (bid < N_CORES) {
    const int seg = bid;
    const int start = corelen[seg];
    const int end = (seg + 1 < N_CORES) ? corelen[seg + 1] : N_ROWS;
    f32x4 a0 = {0.f, 0.f, 0.f, 0.f};
    f32x4 a1 = {0.f, 0.f, 0.f, 0.f};
    f32x4 a2 = {0.f, 0.f, 0.f, 0.f};
    f32x4 a3 = {0.f, 0.f, 0.f, 0.f};
    const f32x4* xp = (const f32x4*)(x + (size_t)start * FEAT) + t;
    int r = start;
    for (; r + 4 <= end; r += 4) {
      const f32x4 v0 = __builtin_nontemporal_load(xp);
      const f32x4 v1 = __builtin_nontemporal_load(xp + 256);
      const f32x4 v2 = __builtin_nontemporal_load(xp + 512);
      const f32x4 v3 = __builtin_nontemporal_load(xp + 768);
      a0 += v0; a1 += v1; a2 += v2; a3 += v3;
      xp += 4 * 256;
    }
    for (; r < end; ++r) {
      a0 += *xp;
      xp += 256;
    }
    a0 += a1; a2 += a3; a0 += a2;
    ushort4 o;
    o.x = f2bf(a0.x); o.y = f2bf(a0.y); o.z = f2bf(a0.z); o.w = f2bf(a0.w);
    *(ushort4*)(aggb + (size_t)seg * FEAT + t * 4) = o;
  } else if (bid < N_CORES + 3 * 1024) {
    __shared__ unsigned short tile[32][33];
    const int id = bid - N_CORES;
    const int l = id >> 10;           // layer 0..2
    const int q = id & 1023;
    const int n0 = (q & 31) * 32;
    const int k0 = (q >> 5) * 32;
    const float* W = (l == 0) ? W1 : (l == 1) ? W2 : W3;
    unsigned short* Wo = Wt + (size_t)l * HDIM * HDIM;
    const int tx = t & 31, ty = t >> 5;
#pragma unroll
    for (int i = 0; i < 4; ++i)
      tile[ty + 8 * i][tx] = f2bf(W[(size_t)(k0 + ty + 8 * i) * HDIM + n0 + tx]);
    __syncthreads();
#pragma unroll
    for (int i = 0; i < 4; ++i)
      Wo[(size_t)(n0 + ty + 8 * i) * HDIM + k0 + tx] = tile[tx][ty + 8 * i];
  } else {
    // zero 6*1024 f32 stats; init out[4096*2] = b4 (layer-3 atomics target)
#pragma unroll
    for (int i = 0; i < 24; ++i) stats[t + i * 256] = 0.f;
    const float bv0 = b4[0], bv1 = b4[1];
#pragma unroll
    for (int i = 0; i < 32; ++i) {
      const int idx = t + i * 256;
      out[idx] = (idx & 1) ? bv1 : bv0;
    }
  }
}

// ---------------- cooperative fused layer: GEMM -> stats -> grid.sync ->
// normalize+ReLU from REGISTERS (no Hb round-trip). is_final: epilogue
// computes the [*,2] output dot instead (atomicAdd into b4-initialized out).
// GEMM body = R8/R12's verified single-wave 64x64 BK=64 counted-vmcnt kernel.
#define BM 64
#define BN 64
#define BK 64
#define NT (HDIM / BK)
__global__ __launch_bounds__(64)
void k_layer(const unsigned short* __restrict__ A,
             const unsigned short* __restrict__ Bt,
             const float* __restrict__ bias,
             const float* __restrict__ g, const float* __restrict__ be,
             float* __restrict__ sums, float* __restrict__ sumsq,
             unsigned short* __restrict__ Aout,
             const float* __restrict__ W4, float* __restrict__ out,
             int is_final) {
  __shared__ unsigned short As[2][BM * BK];
  __shared__ unsigned short Bs[2][BN * BK];
  const int lane = threadIdx.x;   // 0..63, one wave
  const int bid = blockIdx.x;     // 1024 = 64 Mtiles x 16 Ntiles (M fastest)
  const int tileM = (bid & 63) * BM;
  const int tileN = (bid >> 6) * BN;
  const int fr = lane & 15;
  const int kk = (lane >> 4) * 8;
  const int lr = lane >> 3;                       // 0..7
  const int sc = ((lane & 7) * 8) ^ (lr << 3);    // swizzled source k-col

  const unsigned short* pA = A + (size_t)(tileM + lr) * HDIM + sc;
  const unsigned short* pB = Bt + (size_t)(tileN + lr) * HDIM + sc;

  f32x4 acc[4][4] = {};

#define STAGE(buf, k0)                                                     \
  do {                                                                     \
    _Pragma("unroll") for (int j = 0; j < 8; ++j)                          \
        gll16(pA + (k0) + j * 8 * HDIM, &As[buf][(j * 8) * BK]);           \
    _Pragma("unroll") for (int j = 0; j < 8; ++j)                          \
        gll16(pB + (k0) + j * 8 * HDIM, &Bs[buf][(j * 8) * BK]);           \
  } while (0)

  STAGE(0, 0);
  STAGE(1, BK);
  for (int kt = 0; kt < NT; ++kt) {
    const int cur = kt & 1;
    if (kt < NT - 1)
      asm volatile("s_waitcnt vmcnt(16)" ::: "memory");
    else
      asm volatile("s_waitcnt vmcnt(0)" ::: "memory");
    __builtin_amdgcn_sched_barrier(0);
    bf16x8 af[2][4], bfv[2][4];
#pragma unroll
    for (int ks = 0; ks < 2; ++ks) {
      const int pc = (ks * 32 + kk) ^ ((fr & 7) << 3);  // swizzled read col
#pragma unroll
      for (int m = 0; m < 4; ++m)
        af[ks][m] = *(const bf16x8*)&As[cur][(m * 16 + fr) * BK + pc];
#pragma unroll
      for (int n = 0; n < 4; ++n)
        bfv[ks][n] = *(const bf16x8*)&Bs[cur][(n * 16 + fr) * BK + pc];
    }
    asm volatile("s_waitcnt lgkmcnt(0)" ::: "memory");
    __builtin_amdgcn_sched_barrier(0);
    if (kt + 2 < NT) STAGE(cur, (kt + 2) * BK);
#pragma unroll
    for (int ks = 0; ks < 2; ++ks)
#pragma unroll
      for (int m = 0; m < 4; ++m)
#pragma unroll
        for (int n = 0; n < 4; ++n)
          acc[m][n] = __builtin_amdgcn_mfma_f32_16x16x32_bf16(
              af[ks][m], bfv[ks][n], acc[m][n], 0, 0, 0);
  }
#undef STAGE

  // ---- per-column partial BN stats from registers
  const int cr = (lane >> 4) * 4;
  const int cc = lane & 15;
  float bv[4];
#pragma unroll
  for (int n = 0; n < 4; ++n) {
    const int col = tileN + n * 16 + cc;
    bv[n] = bias[col];
    float s = 0.f, s2 = 0.f;
#pragma unroll
    for (int m = 0; m < 4; ++m)
#pragma unroll
      for (int j = 0; j < 4; ++j) {
        const float h = acc[m][n][j] + bv[n];
        s += h; s2 += h * h;
      }
    s  += __shfl_xor(s, 16, 64);  s  += __shfl_xor(s, 32, 64);
    s2 += __shfl_xor(s2, 16, 64); s2 += __shfl_xor(s2, 32, 64);
    if ((lane >> 4) == 0) {
      atomicAdd(&sums[col], s);
      atomicAdd(&sumsq[col], s2);
    }
  }

  __threadfence();
  cg::this_grid().sync();   // all blocks' stats visible

  // ---- per-column scale/shift, normalize the in-register accumulators
  float scl[4], shf[4];
#pragma unroll
  for (int n = 0; n < 4; ++n) {
    const int col = tileN + n * 16 + cc;
    const float mean = sums[col] * (1.f / N_CORES);
    const float var = sumsq[col] * (1.f / N_CORES) - mean * mean;
    const float scv = g[col] * rsqrtf(var + BN_EPS);
    scl[n] = scv;
    shf[n] = be[col] - mean * scv;
  }

  if (!is_final) {
#pragma unroll
    for (int n = 0; n < 4; ++n) {
      const int col = tileN + n * 16 + cc;
      unsigned short* cp = Aout + (size_t)(tileM + cr) * HDIM + col;
#pragma unroll
      for (int m = 0; m < 4; ++m)
#pragma unroll
        for (int j = 0; j < 4; ++j) {
          const float h = acc[m][n][j] + bv[n];
          cp[(size_t)(m * 16 + j) * HDIM] = f2bf(fmaxf(h * scl[n] + shf[n], 0.f));
        }
    }
  } else {
    // layer 3: normalized activation dotted with W4 [1024,2]; per-row
    // partials reduced over the 16 lanes sharing a row, atomicAdd into out.
    float w0[4], w1[4];
#pragma unroll
    for (int n = 0; n < 4; ++n) {
      const int col = tileN + n * 16 + cc;
      w0[n] = W4[col * 2 + 0];
      w1[n] = W4[col * 2 + 1];
    }
#pragma unroll
    for (int m = 0; m < 4; ++m)
#pragma unroll
      for (int j = 0; j < 4; ++j) {
        float s0 = 0.f, s1 = 0.f;
#pragma unroll
        for (int n = 0; n < 4; ++n) {
          const float h = acc[m][n][j] + bv[n];
          const float a = fmaxf(h * scl[n] + shf[n], 0.f);
          s0 += a * w0[n];
          s1 += a * w1[n];
        }
#pragma unroll
        for (int off = 1; off < 16; off <<= 1) {
          s0 += __shfl_xor(s0, off, 64);
          s1 += __shfl_xor(s1, off, 64);
        }
        if ((lane & 15) == 0) {
          const int row = tileM + m * 16 + cr + j;
          atomicAdd(&out[row * 2 + 0], s0);
          atomicAdd(&out[row * 2 + 1], s1);
        }
      }
  }
}

extern "C" void kernel_launch(void* const* d_in, const int* in_sizes, int n_in,
                              void* d_out, int out_size, void* d_ws, size_t ws_size,
                              hipStream_t stream) {
  (void)in_sizes; (void)n_in; (void)out_size; (void)ws_size;
  const float* x       = (const float*)d_in[0];
  const int* corelen   = (const int*)d_in[1];
  const float* W1  = (const float*)d_in[2];
  const float* b1  = (const float*)d_in[3];
  const float* g1  = (const float*)d_in[4];
  const float* be1 = (const float*)d_in[5];
  const float* W2  = (const float*)d_in[6];
  const float* b2  = (const float*)d_in[7];
  const float* g2  = (const float*)d_in[8];
  const float* be2 = (const float*)d_in[9];
  const float* W3  = (const float*)d_in[10];
  const float* b3  = (const float*)d_in[11];
  const float* g3  = (const float*)d_in[12];
  const float* be3 = (const float*)d_in[13];
  const float* W4  = (const float*)d_in[14];
  const float* b4  = (const float*)d_in[15];
  float* out = (float*)d_out;

  char* ws = (char*)d_ws;
  unsigned short* Act0 = (unsigned short*)(ws);               //  8 MB activations (ping)
  unsigned short* Act1 = (unsigned short*)(ws + (8u << 20));  //  8 MB activations (pong)
  unsigned short* Wt   = (unsigned short*)(ws + (16u << 20)); //  6 MB 3x[1024,1024] bf16
  float* stats = (float*)(ws + (22u << 20));                  // 6*1024 f32

  // 1 fused prologue dispatch: segsum + 3 transposes + stats/out init
  k_prep<<<N_CORES + 3 * 1024 + 1, 256, 0, stream>>>(
      x, corelen, Act0, W1, W2, W3, Wt, stats, out, b4);

  const float* bs[3]  = {b1, b2, b3};
  const float* gs[3]  = {g1, g2, g3};
  const float* bes[3] = {be1, be2, be3};
  unsigned short* ain[3]  = {Act0, Act1, Act0};
  unsigned short* aout[3] = {Act1, Act0, Act1};  // aout[2] unused (final)
  for (int l = 0; l < 3; ++l) {
    const unsigned short* A = ain[l];
    const unsigned short* B = Wt + (size_t)l * HDIM * HDIM;
    const float* bias = bs[l];
    const float* g = gs[l];
    const float* be = bes[l];
    float* sums  = stats + l * 2 * HDIM;
    float* sumsq = sums + HDIM;
    unsigned short* Ao = aout[l];
    int is_final = (l == 2);
    void* args[] = {(void*)&A, (void*)&B, (void*)&bias, (void*)&g, (void*)&be,
                    (void*)&sums, (void*)&sumsq, (void*)&Ao, (void*)&W4,
                    (void*)&out, (void*)&is_final};
    hipLaunchCooperativeKernel((void*)k_layer, dim3(1024), dim3(64), args, 0,
                               stream);
  }
}

// Round 16
// 567.132 us; speedup vs baseline: 1.1361x; 1.1361x over previous
//
#include <hip/hip_runtime.h>
#include <hip/hip_bf16.h>
#include <stdint.h>

#define N_ROWS 262144
#define FEAT 1024
#define N_CORES 4096
#define HDIM 1024
#define BN_EPS 1e-5f
#define NBLK 1024   // k_layer grid; 32KB LDS -> 5 blocks/CU -> 1280 capacity

typedef __attribute__((ext_vector_type(8))) short bf16x8;
typedef __attribute__((ext_vector_type(4))) float f32x4;

__device__ __forceinline__ unsigned short f2bf(float f) {
  __hip_bfloat16 h = __float2bfloat16(f);
  return __builtin_bit_cast(unsigned short, h);
}

// async global->LDS, 16B per lane, dest = wave-uniform base + lane*16
__device__ __forceinline__ void gll16(const unsigned short* g, unsigned short* l) {
  __builtin_amdgcn_global_load_lds(
      (const __attribute__((address_space(1))) void*)g,
      (__attribute__((address_space(3))) void*)l, 16, 0, 0);
}

// --------------- PREP mega-kernel: segsum | weight transpose | stats/out init
__global__ __launch_bounds__(256)
void k_prep(const float* __restrict__ x, const int* __restrict__ corelen,
            unsigned short* __restrict__ aggb,
            const float* __restrict__ W1, const float* __restrict__ W2,
            const float* __restrict__ W3, unsigned short* __restrict__ Wt,
            float* __restrict__ stats, int* __restrict__ counters,
            float* __restrict__ out, const float* __restrict__ b4) {
  const int bid = blockIdx.x;
  const int t = threadIdx.x;
  if (bid < N_CORES) {
    const int seg = bid;
    const int start = corelen[seg];
    const int end = (seg + 1 < N_CORES) ? corelen[seg + 1] : N_ROWS;
    f32x4 a0 = {0.f, 0.f, 0.f, 0.f};
    f32x4 a1 = {0.f, 0.f, 0.f, 0.f};
    f32x4 a2 = {0.f, 0.f, 0.f, 0.f};
    f32x4 a3 = {0.f, 0.f, 0.f, 0.f};
    const f32x4* xp = (const f32x4*)(x + (size_t)start * FEAT) + t;
    int r = start;
    for (; r + 4 <= end; r += 4) {
      const f32x4 v0 = __builtin_nontemporal_load(xp);
      const f32x4 v1 = __builtin_nontemporal_load(xp + 256);
      const f32x4 v2 = __builtin_nontemporal_load(xp + 512);
      const f32x4 v3 = __builtin_nontemporal_load(xp + 768);
      a0 += v0; a1 += v1; a2 += v2; a3 += v3;
      xp += 4 * 256;
    }
    for (; r < end; ++r) {
      a0 += *xp;
      xp += 256;
    }
    a0 += a1; a2 += a3; a0 += a2;
    ushort4 o;
    o.x = f2bf(a0.x); o.y = f2bf(a0.y); o.z = f2bf(a0.z); o.w = f2bf(a0.w);
    *(ushort4*)(aggb + (size_t)seg * FEAT + t * 4) = o;
  } else if (bid < N_CORES + 3 * 1024) {
    __shared__ unsigned short tile[32][33];
    const int id = bid - N_CORES;
    const int l = id >> 10;           // layer 0..2
    const int q = id & 1023;
    const int n0 = (q & 31) * 32;
    const int k0 = (q >> 5) * 32;
    const float* W = (l == 0) ? W1 : (l == 1) ? W2 : W3;
    unsigned short* Wo = Wt + (size_t)l * HDIM * HDIM;
    const int tx = t & 31, ty = t >> 5;
#pragma unroll
    for (int i = 0; i < 4; ++i)
      tile[ty + 8 * i][tx] = f2bf(W[(size_t)(k0 + ty + 8 * i) * HDIM + n0 + tx]);
    __syncthreads();
#pragma unroll
    for (int i = 0; i < 4; ++i)
      Wo[(size_t)(n0 + ty + 8 * i) * HDIM + k0 + tx] = tile[tx][ty + 8 * i];
  } else {
    // zero stats + barrier counters; init out[4096*2] = b4
#pragma unroll
    for (int i = 0; i < 24; ++i) stats[t + i * 256] = 0.f;
    if (t < 3) counters[t] = 0;
    const float bv0 = b4[0], bv1 = b4[1];
#pragma unroll
    for (int i = 0; i < 32; ++i) {
      const int idx = t + i * 256;
      out[idx] = (idx & 1) ? bv1 : bv0;
    }
  }
}

// ---------------- fused layer (regular launch): GEMM -> stats atomics ->
// hand-rolled device-scope stats barrier (R15 lesson: cooperative launch is
// correct but +131us/launch in graph replay; this barrier is the same sync
// with regular dispatch) -> in-register normalize+ReLU -> write activations
// (or, is_final: the [*,2] output dot via atomicAdd into b4-initialized out).
// Co-residency: 32KB LDS -> 5 blocks/CU -> capacity 1280 >= grid 1024
// (proven co-resident by R15's passing cooperative run).
#define BM 64
#define BN 64
#define BK 64
#define NT (HDIM / BK)
__global__ __launch_bounds__(64)
void k_layer(const unsigned short* __restrict__ A,
             const unsigned short* __restrict__ Bt,
             const float* __restrict__ bias,
             const float* __restrict__ g, const float* __restrict__ be,
             float* __restrict__ sums, float* __restrict__ sumsq,
             int* __restrict__ counter,
             unsigned short* __restrict__ Aout,
             const float* __restrict__ W4, float* __restrict__ out,
             int is_final) {
  __shared__ unsigned short As[2][BM * BK];
  __shared__ unsigned short Bs[2][BN * BK];
  const int lane = threadIdx.x;   // 0..63, one wave
  const int bid = blockIdx.x;     // 1024 = 64 Mtiles x 16 Ntiles
  const int tileM = (bid & 63) * BM;
  const int tileN = (bid >> 6) * BN;
  const int fr = lane & 15;
  const int kk = (lane >> 4) * 8;
  const int lr = lane >> 3;                       // 0..7
  const int sc = ((lane & 7) * 8) ^ (lr << 3);    // swizzled source k-col

  const unsigned short* pA = A + (size_t)(tileM + lr) * HDIM + sc;
  const unsigned short* pB = Bt + (size_t)(tileN + lr) * HDIM + sc;

  f32x4 acc[4][4] = {};

#define STAGE(buf, k0)                                                     \
  do {                                                                     \
    _Pragma("unroll") for (int j = 0; j < 8; ++j)                          \
        gll16(pA + (k0) + j * 8 * HDIM, &As[buf][(j * 8) * BK]);           \
    _Pragma("unroll") for (int j = 0; j < 8; ++j)                          \
        gll16(pB + (k0) + j * 8 * HDIM, &Bs[buf][(j * 8) * BK]);           \
  } while (0)

  STAGE(0, 0);
  STAGE(1, BK);
  for (int kt = 0; kt < NT; ++kt) {
    const int cur = kt & 1;
    if (kt < NT - 1)
      asm volatile("s_waitcnt vmcnt(16)" ::: "memory");
    else
      asm volatile("s_waitcnt vmcnt(0)" ::: "memory");
    __builtin_amdgcn_sched_barrier(0);
    bf16x8 af[2][4], bfv[2][4];
#pragma unroll
    for (int ks = 0; ks < 2; ++ks) {
      const int pc = (ks * 32 + kk) ^ ((fr & 7) << 3);  // swizzled read col
#pragma unroll
      for (int m = 0; m < 4; ++m)
        af[ks][m] = *(const bf16x8*)&As[cur][(m * 16 + fr) * BK + pc];
#pragma unroll
      for (int n = 0; n < 4; ++n)
        bfv[ks][n] = *(const bf16x8*)&Bs[cur][(n * 16 + fr) * BK + pc];
    }
    asm volatile("s_waitcnt lgkmcnt(0)" ::: "memory");
    __builtin_amdgcn_sched_barrier(0);
    if (kt + 2 < NT) STAGE(cur, (kt + 2) * BK);
#pragma unroll
    for (int ks = 0; ks < 2; ++ks)
#pragma unroll
      for (int m = 0; m < 4; ++m)
#pragma unroll
        for (int n = 0; n < 4; ++n)
          acc[m][n] = __builtin_amdgcn_mfma_f32_16x16x32_bf16(
              af[ks][m], bfv[ks][n], acc[m][n], 0, 0, 0);
  }
#undef STAGE

  // ---- per-column partial BN stats from registers
  const int cr = (lane >> 4) * 4;
  const int cc = lane & 15;
  float bv[4];
#pragma unroll
  for (int n = 0; n < 4; ++n) {
    const int col = tileN + n * 16 + cc;
    bv[n] = bias[col];
    float s = 0.f, s2 = 0.f;
#pragma unroll
    for (int m = 0; m < 4; ++m)
#pragma unroll
      for (int j = 0; j < 4; ++j) {
        const float h = acc[m][n][j] + bv[n];
        s += h; s2 += h * h;
      }
    s  += __shfl_xor(s, 16, 64);  s  += __shfl_xor(s, 32, 64);
    s2 += __shfl_xor(s2, 16, 64); s2 += __shfl_xor(s2, 32, 64);
    if ((lane >> 4) == 0) {
      atomicAdd(&sums[col], s);
      atomicAdd(&sumsq[col], s2);
    }
  }

  // ---- hand-rolled device-scope stats barrier
  __threadfence();   // my stats atomics visible before signaling
  if (lane == 0)
    __hip_atomic_fetch_add(counter, 1, __ATOMIC_RELEASE,
                           __HIP_MEMORY_SCOPE_AGENT);
  while (__hip_atomic_load(counter, __ATOMIC_ACQUIRE,
                           __HIP_MEMORY_SCOPE_AGENT) < NBLK)
    __builtin_amdgcn_s_sleep(8);
  __threadfence();

  // ---- per-column scale/shift (coherent AGENT-scope loads of stats)
  float scl[4], shf[4];
#pragma unroll
  for (int n = 0; n < 4; ++n) {
    const int col = tileN + n * 16 + cc;
    const float sv = __hip_atomic_load(&sums[col], __ATOMIC_RELAXED,
                                       __HIP_MEMORY_SCOPE_AGENT);
    const float qv = __hip_atomic_load(&sumsq[col], __ATOMIC_RELAXED,
                                       __HIP_MEMORY_SCOPE_AGENT);
    const float mean = sv * (1.f / N_CORES);
    const float var = qv * (1.f / N_CORES) - mean * mean;
    const float scv = g[col] * rsqrtf(var + BN_EPS);
    scl[n] = scv;
    shf[n] = be[col] - mean * scv;
  }

  if (!is_final) {
#pragma unroll
    for (int n = 0; n < 4; ++n) {
      const int col = tileN + n * 16 + cc;
      unsigned short* cp = Aout + (size_t)(tileM + cr) * HDIM + col;
#pragma unroll
      for (int m = 0; m < 4; ++m)
#pragma unroll
        for (int j = 0; j < 4; ++j) {
          const float h = acc[m][n][j] + bv[n];
          cp[(size_t)(m * 16 + j) * HDIM] = f2bf(fmaxf(h * scl[n] + shf[n], 0.f));
        }
    }
  } else {
    float w0[4], w1[4];
#pragma unroll
    for (int n = 0; n < 4; ++n) {
      const int col = tileN + n * 16 + cc;
      w0[n] = W4[col * 2 + 0];
      w1[n] = W4[col * 2 + 1];
    }
#pragma unroll
    for (int m = 0; m < 4; ++m)
#pragma unroll
      for (int j = 0; j < 4; ++j) {
        float s0 = 0.f, s1 = 0.f;
#pragma unroll
        for (int n = 0; n < 4; ++n) {
          const float h = acc[m][n][j] + bv[n];
          const float a = fmaxf(h * scl[n] + shf[n], 0.f);
          s0 += a * w0[n];
          s1 += a * w1[n];
        }
#pragma unroll
        for (int off = 1; off < 16; off <<= 1) {
          s0 += __shfl_xor(s0, off, 64);
          s1 += __shfl_xor(s1, off, 64);
        }
        if ((lane & 15) == 0) {
          const int row = tileM + m * 16 + cr + j;
          atomicAdd(&out[row * 2 + 0], s0);
          atomicAdd(&out[row * 2 + 1], s1);
        }
      }
  }
}

extern "C" void kernel_launch(void* const* d_in, const int* in_sizes, int n_in,
                              void* d_out, int out_size, void* d_ws, size_t ws_size,
                              hipStream_t stream) {
  (void)in_sizes; (void)n_in; (void)out_size; (void)ws_size;
  const float* x       = (const float*)d_in[0];
  const int* corelen   = (const int*)d_in[1];
  const float* W1  = (const float*)d_in[2];
  const float* b1  = (const float*)d_in[3];
  const float* g1  = (const float*)d_in[4];
  const float* be1 = (const float*)d_in[5];
  const float* W2  = (const float*)d_in[6];
  const float* b2  = (const float*)d_in[7];
  const float* g2  = (const float*)d_in[8];
  const float* be2 = (const float*)d_in[9];
  const float* W3  = (const float*)d_in[10];
  const float* b3  = (const float*)d_in[11];
  const float* g3  = (const float*)d_in[12];
  const float* be3 = (const float*)d_in[13];
  const float* W4  = (const float*)d_in[14];
  const float* b4  = (const float*)d_in[15];
  float* out = (float*)d_out;

  char* ws = (char*)d_ws;
  unsigned short* Act0 = (unsigned short*)(ws);               //  8 MB activations (ping)
  unsigned short* Act1 = (unsigned short*)(ws + (8u << 20));  //  8 MB activations (pong)
  unsigned short* Wt   = (unsigned short*)(ws + (16u << 20)); //  6 MB 3x[1024,1024] bf16
  float* stats = (float*)(ws + (22u << 20));                  // 6*1024 f32
  int* counters = (int*)(stats + 6 * HDIM);                   // 3 barrier counters

  // 1 fused prologue dispatch: segsum + 3 transposes + stats/counters/out init
  k_prep<<<N_CORES + 3 * 1024 + 1, 256, 0, stream>>>(
      x, corelen, Act0, W1, W2, W3, Wt, stats, counters, out, b4);

  const float* bs[3]  = {b1, b2, b3};
  const float* gs[3]  = {g1, g2, g3};
  const float* bes[3] = {be1, be2, be3};
  unsigned short* ain[3]  = {Act0, Act1, Act0};
  unsigned short* aout[3] = {Act1, Act0, Act1};  // aout[2] unused (final)
  for (int l = 0; l < 3; ++l) {
    float* sums  = stats + l * 2 * HDIM;
    float* sumsq = sums + HDIM;
    k_layer<<<NBLK, 64, 0, stream>>>(
        ain[l], Wt + (size_t)l * HDIM * HDIM, bs[l], gs[l], bes[l],
        sums, sumsq, counters + l, aout[l], W4, out, (l == 2) ? 1 : 0);
  }
}

// Round 17
// 510.813 us; speedup vs baseline: 1.2614x; 1.1103x over previous
//
#include <hip/hip_runtime.h>
#include <hip/hip_bf16.h>
#include <stdint.h>

#define N_ROWS 262144
#define FEAT 1024
#define N_CORES 4096
#define HDIM 1024
#define BN_EPS 1e-5f
#define NBLK 1024   // k_layer grid; 32KB LDS -> 5 blocks/CU -> 1280 capacity

typedef __attribute__((ext_vector_type(8))) short bf16x8;
typedef __attribute__((ext_vector_type(4))) float f32x4;

__device__ __forceinline__ unsigned short f2bf(float f) {
  __hip_bfloat16 h = __float2bfloat16(f);
  return __builtin_bit_cast(unsigned short, h);
}

// async global->LDS, 16B per lane, dest = wave-uniform base + lane*16
__device__ __forceinline__ void gll16(const unsigned short* g, unsigned short* l) {
  __builtin_amdgcn_global_load_lds(
      (const __attribute__((address_space(1))) void*)g,
      (__attribute__((address_space(3))) void*)l, 16, 0, 0);
}

// --------------- PREP mega-kernel: segsum | weight transpose | stats/out init
__global__ __launch_bounds__(256)
void k_prep(const float* __restrict__ x, const int* __restrict__ corelen,
            unsigned short* __restrict__ aggb,
            const float* __restrict__ W1, const float* __restrict__ W2,
            const float* __restrict__ W3, unsigned short* __restrict__ Wt,
            float* __restrict__ stats, int* __restrict__ counters,
            float* __restrict__ out, const float* __restrict__ b4) {
  const int bid = blockIdx.x;
  const int t = threadIdx.x;
  if (bid < N_CORES) {
    const int seg = bid;
    const int start = corelen[seg];
    const int end = (seg + 1 < N_CORES) ? corelen[seg + 1] : N_ROWS;
    f32x4 a0 = {0.f, 0.f, 0.f, 0.f};
    f32x4 a1 = {0.f, 0.f, 0.f, 0.f};
    f32x4 a2 = {0.f, 0.f, 0.f, 0.f};
    f32x4 a3 = {0.f, 0.f, 0.f, 0.f};
    const f32x4* xp = (const f32x4*)(x + (size_t)start * FEAT) + t;
    int r = start;
    for (; r + 4 <= end; r += 4) {
      const f32x4 v0 = __builtin_nontemporal_load(xp);
      const f32x4 v1 = __builtin_nontemporal_load(xp + 256);
      const f32x4 v2 = __builtin_nontemporal_load(xp + 512);
      const f32x4 v3 = __builtin_nontemporal_load(xp + 768);
      a0 += v0; a1 += v1; a2 += v2; a3 += v3;
      xp += 4 * 256;
    }
    for (; r < end; ++r) {
      a0 += *xp;
      xp += 256;
    }
    a0 += a1; a2 += a3; a0 += a2;
    ushort4 o;
    o.x = f2bf(a0.x); o.y = f2bf(a0.y); o.z = f2bf(a0.z); o.w = f2bf(a0.w);
    *(ushort4*)(aggb + (size_t)seg * FEAT + t * 4) = o;
  } else if (bid < N_CORES + 3 * 1024) {
    __shared__ unsigned short tile[32][33];
    const int id = bid - N_CORES;
    const int l = id >> 10;           // layer 0..2
    const int q = id & 1023;
    const int n0 = (q & 31) * 32;
    const int k0 = (q >> 5) * 32;
    const float* W = (l == 0) ? W1 : (l == 1) ? W2 : W3;
    unsigned short* Wo = Wt + (size_t)l * HDIM * HDIM;
    const int tx = t & 31, ty = t >> 5;
#pragma unroll
    for (int i = 0; i < 4; ++i)
      tile[ty + 8 * i][tx] = f2bf(W[(size_t)(k0 + ty + 8 * i) * HDIM + n0 + tx]);
    __syncthreads();
#pragma unroll
    for (int i = 0; i < 4; ++i)
      Wo[(size_t)(n0 + ty + 8 * i) * HDIM + k0 + tx] = tile[tx][ty + 8 * i];
  } else {
    // zero stats + barrier counters; init out[4096*2] = b4
#pragma unroll
    for (int i = 0; i < 24; ++i) stats[t + i * 256] = 0.f;
    if (t < 3) counters[t] = 0;
    const float bv0 = b4[0], bv1 = b4[1];
#pragma unroll
    for (int i = 0; i < 32; ++i) {
      const int idx = t + i * 256;
      out[idx] = (idx & 1) ? bv1 : bv0;
    }
  }
}

// ---------------- fused layer (regular launch): GEMM -> stats atomics ->
// device-scope stats barrier with RELAXED polling (R16 lesson: ACQUIRE
// atomic loads emit a cache-invalidate PER POLL -- 1024 spinning waves
// annihilated L1/L2 machine-wide, costing ~106us/layer. Relaxed polls
// still bypass non-coherent caches for visibility; one __threadfence()
// after exit provides the single acquire needed) -> in-register
// normalize+ReLU -> activations (or final [*,2] dot via atomicAdd).
#define BM 64
#define BN 64
#define BK 64
#define NT (HDIM / BK)
__global__ __launch_bounds__(64)
void k_layer(const unsigned short* __restrict__ A,
             const unsigned short* __restrict__ Bt,
             const float* __restrict__ bias,
             const float* __restrict__ g, const float* __restrict__ be,
             float* __restrict__ sums, float* __restrict__ sumsq,
             int* __restrict__ counter,
             unsigned short* __restrict__ Aout,
             const float* __restrict__ W4, float* __restrict__ out,
             int is_final) {
  __shared__ unsigned short As[2][BM * BK];
  __shared__ unsigned short Bs[2][BN * BK];
  const int lane = threadIdx.x;   // 0..63, one wave
  const int bid = blockIdx.x;     // 1024 = 64 Mtiles x 16 Ntiles
  const int tileM = (bid & 63) * BM;
  const int tileN = (bid >> 6) * BN;
  const int fr = lane & 15;
  const int kk = (lane >> 4) * 8;
  const int lr = lane >> 3;                       // 0..7
  const int sc = ((lane & 7) * 8) ^ (lr << 3);    // swizzled source k-col

  const unsigned short* pA = A + (size_t)(tileM + lr) * HDIM + sc;
  const unsigned short* pB = Bt + (size_t)(tileN + lr) * HDIM + sc;

  f32x4 acc[4][4] = {};

#define STAGE(buf, k0)                                                     \
  do {                                                                     \
    _Pragma("unroll") for (int j = 0; j < 8; ++j)                          \
        gll16(pA + (k0) + j * 8 * HDIM, &As[buf][(j * 8) * BK]);           \
    _Pragma("unroll") for (int j = 0; j < 8; ++j)                          \
        gll16(pB + (k0) + j * 8 * HDIM, &Bs[buf][(j * 8) * BK]);           \
  } while (0)

  STAGE(0, 0);
  STAGE(1, BK);
  for (int kt = 0; kt < NT; ++kt) {
    const int cur = kt & 1;
    if (kt < NT - 1)
      asm volatile("s_waitcnt vmcnt(16)" ::: "memory");
    else
      asm volatile("s_waitcnt vmcnt(0)" ::: "memory");
    __builtin_amdgcn_sched_barrier(0);
    bf16x8 af[2][4], bfv[2][4];
#pragma unroll
    for (int ks = 0; ks < 2; ++ks) {
      const int pc = (ks * 32 + kk) ^ ((fr & 7) << 3);  // swizzled read col
#pragma unroll
      for (int m = 0; m < 4; ++m)
        af[ks][m] = *(const bf16x8*)&As[cur][(m * 16 + fr) * BK + pc];
#pragma unroll
      for (int n = 0; n < 4; ++n)
        bfv[ks][n] = *(const bf16x8*)&Bs[cur][(n * 16 + fr) * BK + pc];
    }
    asm volatile("s_waitcnt lgkmcnt(0)" ::: "memory");
    __builtin_amdgcn_sched_barrier(0);
    if (kt + 2 < NT) STAGE(cur, (kt + 2) * BK);
#pragma unroll
    for (int ks = 0; ks < 2; ++ks)
#pragma unroll
      for (int m = 0; m < 4; ++m)
#pragma unroll
        for (int n = 0; n < 4; ++n)
          acc[m][n] = __builtin_amdgcn_mfma_f32_16x16x32_bf16(
              af[ks][m], bfv[ks][n], acc[m][n], 0, 0, 0);
  }
#undef STAGE

  // ---- per-column partial BN stats from registers
  const int cr = (lane >> 4) * 4;
  const int cc = lane & 15;
  float bv[4];
#pragma unroll
  for (int n = 0; n < 4; ++n) {
    const int col = tileN + n * 16 + cc;
    bv[n] = bias[col];
    float s = 0.f, s2 = 0.f;
#pragma unroll
    for (int m = 0; m < 4; ++m)
#pragma unroll
      for (int j = 0; j < 4; ++j) {
        const float h = acc[m][n][j] + bv[n];
        s += h; s2 += h * h;
      }
    s  += __shfl_xor(s, 16, 64);  s  += __shfl_xor(s, 32, 64);
    s2 += __shfl_xor(s2, 16, 64); s2 += __shfl_xor(s2, 32, 64);
    if ((lane >> 4) == 0) {
      atomicAdd(&sums[col], s);
      atomicAdd(&sumsq[col], s2);
    }
  }

  // ---- stats barrier: RELAXED polling (no per-poll cache invalidate)
  __threadfence();   // my stats atomics visible before signaling
  if (lane == 0)
    __hip_atomic_fetch_add(counter, 1, __ATOMIC_RELEASE,
                           __HIP_MEMORY_SCOPE_AGENT);
  while (__hip_atomic_load(counter, __ATOMIC_RELAXED,
                           __HIP_MEMORY_SCOPE_AGENT) < NBLK)
    __builtin_amdgcn_s_sleep(32);
  __threadfence();   // single acquire: stats reads below see all atomics

  // ---- per-column scale/shift
  float scl[4], shf[4];
#pragma unroll
  for (int n = 0; n < 4; ++n) {
    const int col = tileN + n * 16 + cc;
    const float sv = __hip_atomic_load(&sums[col], __ATOMIC_RELAXED,
                                       __HIP_MEMORY_SCOPE_AGENT);
    const float qv = __hip_atomic_load(&sumsq[col], __ATOMIC_RELAXED,
                                       __HIP_MEMORY_SCOPE_AGENT);
    const float mean = sv * (1.f / N_CORES);
    const float var = qv * (1.f / N_CORES) - mean * mean;
    const float scv = g[col] * rsqrtf(var + BN_EPS);
    scl[n] = scv;
    shf[n] = be[col] - mean * scv;
  }

  if (!is_final) {
#pragma unroll
    for (int n = 0; n < 4; ++n) {
      const int col = tileN + n * 16 + cc;
      unsigned short* cp = Aout + (size_t)(tileM + cr) * HDIM + col;
#pragma unroll
      for (int m = 0; m < 4; ++m)
#pragma unroll
        for (int j = 0; j < 4; ++j) {
          const float h = acc[m][n][j] + bv[n];
          cp[(size_t)(m * 16 + j) * HDIM] = f2bf(fmaxf(h * scl[n] + shf[n], 0.f));
        }
    }
  } else {
    float w0[4], w1[4];
#pragma unroll
    for (int n = 0; n < 4; ++n) {
      const int col = tileN + n * 16 + cc;
      w0[n] = W4[col * 2 + 0];
      w1[n] = W4[col * 2 + 1];
    }
#pragma unroll
    for (int m = 0; m < 4; ++m)
#pragma unroll
      for (int j = 0; j < 4; ++j) {
        float s0 = 0.f, s1 = 0.f;
#pragma unroll
        for (int n = 0; n < 4; ++n) {
          const float h = acc[m][n][j] + bv[n];
          const float a = fmaxf(h * scl[n] + shf[n], 0.f);
          s0 += a * w0[n];
          s1 += a * w1[n];
        }
#pragma unroll
        for (int off = 1; off < 16; off <<= 1) {
          s0 += __shfl_xor(s0, off, 64);
          s1 += __shfl_xor(s1, off, 64);
        }
        if ((lane & 15) == 0) {
          const int row = tileM + m * 16 + cr + j;
          atomicAdd(&out[row * 2 + 0], s0);
          atomicAdd(&out[row * 2 + 1], s1);
        }
      }
  }
}

extern "C" void kernel_launch(void* const* d_in, const int* in_sizes, int n_in,
                              void* d_out, int out_size, void* d_ws, size_t ws_size,
                              hipStream_t stream) {
  (void)in_sizes; (void)n_in; (void)out_size; (void)ws_size;
  const float* x       = (const float*)d_in[0];
  const int* corelen   = (const int*)d_in[1];
  const float* W1  = (const float*)d_in[2];
  const float* b1  = (const float*)d_in[3];
  const float* g1  = (const float*)d_in[4];
  const float* be1 = (const float*)d_in[5];
  const float* W2  = (const float*)d_in[6];
  const float* b2  = (const float*)d_in[7];
  const float* g2  = (const float*)d_in[8];
  const float* be2 = (const float*)d_in[9];
  const float* W3  = (const float*)d_in[10];
  const float* b3  = (const float*)d_in[11];
  const float* g3  = (const float*)d_in[12];
  const float* be3 = (const float*)d_in[13];
  const float* W4  = (const float*)d_in[14];
  const float* b4  = (const float*)d_in[15];
  float* out = (float*)d_out;

  char* ws = (char*)d_ws;
  unsigned short* Act0 = (unsigned short*)(ws);               //  8 MB activations (ping)
  unsigned short* Act1 = (unsigned short*)(ws + (8u << 20));  //  8 MB activations (pong)
  unsigned short* Wt   = (unsigned short*)(ws + (16u << 20)); //  6 MB 3x[1024,1024] bf16
  float* stats = (float*)(ws + (22u << 20));                  // 6*1024 f32
  int* counters = (int*)(stats + 6 * HDIM);                   // 3 barrier counters

  // 1 fused prologue dispatch: segsum + 3 transposes + stats/counters/out init
  k_prep<<<N_CORES + 3 * 1024 + 1, 256, 0, stream>>>(
      x, corelen, Act0, W1, W2, W3, Wt, stats, counters, out, b4);

  const float* bs[3]  = {b1, b2, b3};
  const float* gs[3]  = {g1, g2, g3};
  const float* bes[3] = {be1, be2, be3};
  unsigned short* ain[3]  = {Act0, Act1, Act0};
  unsigned short* aout[3] = {Act1, Act0, Act1};  // aout[2] unused (final)
  for (int l = 0; l < 3; ++l) {
    float* sums  = stats + l * 2 * HDIM;
    float* sumsq = sums + HDIM;
    k_layer<<<NBLK, 64, 0, stream>>>(
        ain[l], Wt + (size_t)l * HDIM * HDIM, bs[l], gs[l], bes[l],
        sums, sumsq, counters + l, aout[l], W4, out, (l == 2) ? 1 : 0);
  }
}

// Round 18
// 250.110 us; speedup vs baseline: 2.5762x; 2.0424x over previous
//
#include <hip/hip_runtime.h>
#include <hip/hip_bf16.h>
#include <stdint.h>

#define N_ROWS 262144
#define FEAT 1024
#define N_CORES 4096
#define HDIM 1024
#define BN_EPS 1e-5f

typedef __attribute__((ext_vector_type(8))) short bf16x8;
typedef __attribute__((ext_vector_type(8))) unsigned short u16x8;
typedef __attribute__((ext_vector_type(4))) float f32x4;

__device__ __forceinline__ unsigned short f2bf(float f) {
  __hip_bfloat16 h = __float2bfloat16(f);
  return __builtin_bit_cast(unsigned short, h);
}
__device__ __forceinline__ float bf2f(unsigned short u) {
  unsigned int x = ((unsigned int)u) << 16;
  return __builtin_bit_cast(float, x);
}

// async global->LDS, 16B per lane, dest = wave-uniform base + lane*16
__device__ __forceinline__ void gll16(const unsigned short* g, unsigned short* l) {
  __builtin_amdgcn_global_load_lds(
      (const __attribute__((address_space(1))) void*)g,
      (__attribute__((address_space(3))) void*)l, 16, 0, 0);
}

// --------------- PREP mega-kernel: segsum | weight transpose | stats zero
// R18: segsum now 8-row unroll (8 independent acc chains, 128B/lane in
// flight) -- last MLP lever on the 152us/7.06 TB/s read stream.
__global__ __launch_bounds__(256)
void k_prep(const float* __restrict__ x, const int* __restrict__ corelen,
            unsigned short* __restrict__ aggb,
            const float* __restrict__ W1, const float* __restrict__ W2,
            const float* __restrict__ W3, unsigned short* __restrict__ Wt,
            float* __restrict__ stats) {
  const int bid = blockIdx.x;
  const int t = threadIdx.x;
  if (bid < N_CORES) {
    const int seg = bid;
    const int start = corelen[seg];
    const int end = (seg + 1 < N_CORES) ? corelen[seg + 1] : N_ROWS;
    f32x4 a0 = {0.f, 0.f, 0.f, 0.f};
    f32x4 a1 = {0.f, 0.f, 0.f, 0.f};
    f32x4 a2 = {0.f, 0.f, 0.f, 0.f};
    f32x4 a3 = {0.f, 0.f, 0.f, 0.f};
    f32x4 a4 = {0.f, 0.f, 0.f, 0.f};
    f32x4 a5 = {0.f, 0.f, 0.f, 0.f};
    f32x4 a6 = {0.f, 0.f, 0.f, 0.f};
    f32x4 a7 = {0.f, 0.f, 0.f, 0.f};
    const f32x4* xp = (const f32x4*)(x + (size_t)start * FEAT) + t;
    int r = start;
    for (; r + 8 <= end; r += 8) {
      const f32x4 v0 = __builtin_nontemporal_load(xp);
      const f32x4 v1 = __builtin_nontemporal_load(xp + 256);
      const f32x4 v2 = __builtin_nontemporal_load(xp + 512);
      const f32x4 v3 = __builtin_nontemporal_load(xp + 768);
      const f32x4 v4 = __builtin_nontemporal_load(xp + 1024);
      const f32x4 v5 = __builtin_nontemporal_load(xp + 1280);
      const f32x4 v6 = __builtin_nontemporal_load(xp + 1536);
      const f32x4 v7 = __builtin_nontemporal_load(xp + 1792);
      a0 += v0; a1 += v1; a2 += v2; a3 += v3;
      a4 += v4; a5 += v5; a6 += v6; a7 += v7;
      xp += 8 * 256;
    }
    for (; r < end; ++r) {
      a0 += *xp;
      xp += 256;
    }
    a0 += a1; a2 += a3; a4 += a5; a6 += a7;
    a0 += a2; a4 += a6; a0 += a4;
    ushort4 o;
    o.x = f2bf(a0.x); o.y = f2bf(a0.y); o.z = f2bf(a0.z); o.w = f2bf(a0.w);
    *(ushort4*)(aggb + (size_t)seg * FEAT + t * 4) = o;
  } else if (bid < N_CORES + 3 * 1024) {
    __shared__ unsigned short tile[32][33];
    const int id = bid - N_CORES;
    const int l = id >> 10;           // layer 0..2
    const int q = id & 1023;
    const int n0 = (q & 31) * 32;
    const int k0 = (q >> 5) * 32;
    const float* W = (l == 0) ? W1 : (l == 1) ? W2 : W3;
    unsigned short* Wo = Wt + (size_t)l * HDIM * HDIM;
    const int tx = t & 31, ty = t >> 5;
#pragma unroll
    for (int i = 0; i < 4; ++i)
      tile[ty + 8 * i][tx] = f2bf(W[(size_t)(k0 + ty + 8 * i) * HDIM + n0 + tx]);
    __syncthreads();
#pragma unroll
    for (int i = 0; i < 4; ++i)
      Wo[(size_t)(n0 + ty + 8 * i) * HDIM + k0 + tx] = tile[tx][ty + 8 * i];
  } else {
#pragma unroll
    for (int i = 0; i < 24; ++i) stats[t + i * 256] = 0.f;
  }
}

// ------------------------------------------------------------------ GEMM
// R8/R12's verified BK=64 single-wave kernel (14.6 us/dispatch, R9).
// R15-R17 lesson: in-dispatch grid-wide sync (cooperative, acquire-spin,
// relaxed-spin) all cost 87-131us/layer -- far more than the ~6us dispatch
// gap it would save. Dispatch-boundary sync is optimal on this chip.
#define BM 64
#define BN 64
#define BK 64
#define NT (HDIM / BK)
__global__ __launch_bounds__(64)
void k_gemm_bt(const unsigned short* __restrict__ A,
               const unsigned short* __restrict__ Bt,
               const float* __restrict__ bias,
               unsigned short* __restrict__ C,
               float* __restrict__ sums, float* __restrict__ sumsq) {
  __shared__ unsigned short As[2][BM * BK];
  __shared__ unsigned short Bs[2][BN * BK];
  const int lane = threadIdx.x;   // 0..63, one wave
  const int tileM = blockIdx.x * BM;
  const int tileN = blockIdx.y * BN;
  const int fr = lane & 15;
  const int kk = (lane >> 4) * 8;
  const int lr = lane >> 3;                       // 0..7
  const int sc = ((lane & 7) * 8) ^ (lr << 3);    // swizzled source k-col

  const unsigned short* pA = A + (size_t)(tileM + lr) * HDIM + sc;
  const unsigned short* pB = Bt + (size_t)(tileN + lr) * HDIM + sc;

  f32x4 acc[4][4] = {};

#define STAGE(buf, k0)                                                     \
  do {                                                                     \
    _Pragma("unroll") for (int j = 0; j < 8; ++j)                          \
        gll16(pA + (k0) + j * 8 * HDIM, &As[buf][(j * 8) * BK]);           \
    _Pragma("unroll") for (int j = 0; j < 8; ++j)                          \
        gll16(pB + (k0) + j * 8 * HDIM, &Bs[buf][(j * 8) * BK]);           \
  } while (0)

  STAGE(0, 0);
  STAGE(1, BK);
  for (int kt = 0; kt < NT; ++kt) {
    const int cur = kt & 1;
    if (kt < NT - 1)
      asm volatile("s_waitcnt vmcnt(16)" ::: "memory");
    else
      asm volatile("s_waitcnt vmcnt(0)" ::: "memory");
    __builtin_amdgcn_sched_barrier(0);
    bf16x8 af[2][4], bfv[2][4];
#pragma unroll
    for (int ks = 0; ks < 2; ++ks) {
      const int pc = (ks * 32 + kk) ^ ((fr & 7) << 3);  // swizzled read col
#pragma unroll
      for (int m = 0; m < 4; ++m)
        af[ks][m] = *(const bf16x8*)&As[cur][(m * 16 + fr) * BK + pc];
#pragma unroll
      for (int n = 0; n < 4; ++n)
        bfv[ks][n] = *(const bf16x8*)&Bs[cur][(n * 16 + fr) * BK + pc];
    }
    asm volatile("s_waitcnt lgkmcnt(0)" ::: "memory");
    __builtin_amdgcn_sched_barrier(0);
    if (kt + 2 < NT) STAGE(cur, (kt + 2) * BK);
#pragma unroll
    for (int ks = 0; ks < 2; ++ks)
#pragma unroll
      for (int m = 0; m < 4; ++m)
#pragma unroll
        for (int n = 0; n < 4; ++n)
          acc[m][n] = __builtin_amdgcn_mfma_f32_16x16x32_bf16(
              af[ks][m], bfv[ks][n], acc[m][n], 0, 0, 0);
  }
#undef STAGE

  // epilogue: bias, store bf16 H, fused per-column partial BN stats (f32)
  const int cr = (lane >> 4) * 4;
  const int cc = lane & 15;
#pragma unroll
  for (int n = 0; n < 4; ++n) {
    const int col = tileN + n * 16 + cc;
    const float bv = bias[col];
    float s = 0.f, s2 = 0.f;
#pragma unroll
    for (int m = 0; m < 4; ++m) {
      unsigned short* cp = C + (size_t)(tileM + m * 16 + cr) * HDIM + col;
#pragma unroll
      for (int j = 0; j < 4; ++j) {
        const float h = acc[m][n][j] + bv;
        cp[(size_t)j * HDIM] = f2bf(h);
        s += h; s2 += h * h;
      }
    }
    s  += __shfl_xor(s, 16, 64);  s  += __shfl_xor(s, 32, 64);
    s2 += __shfl_xor(s2, 16, 64); s2 += __shfl_xor(s2, 32, 64);
    if ((lane >> 4) == 0) {
      atomicAdd(&sums[col], s);
      atomicAdd(&sumsq[col], s2);
    }
  }
}

// ------------------- normalize + ReLU, finalize fused (8 rsqrt/thread)
__global__ __launch_bounds__(256)
void k_norm_relu(const unsigned short* __restrict__ Hb,
                 const float* __restrict__ sums, const float* __restrict__ sumsq,
                 const float* __restrict__ g, const float* __restrict__ be,
                 unsigned short* __restrict__ Ab) {
  const size_t i8 = ((size_t)blockIdx.x * 256 + threadIdx.x) * 8;
  const u16x8 v = *(const u16x8*)(Hb + i8);
  const int c = (int)(i8 & (HDIM - 1));
  u16x8 o;
#pragma unroll
  for (int j = 0; j < 8; ++j) {
    const float mean = sums[c + j] * (1.f / N_CORES);
    const float var = sumsq[c + j] * (1.f / N_CORES) - mean * mean;
    const float sc = g[c + j] * rsqrtf(var + BN_EPS);
    const float sh = be[c + j] - mean * sc;
    o[j] = f2bf(fmaxf(bf2f(v[j]) * sc + sh, 0.f));
  }
  *(u16x8*)(Ab + i8) = o;
}

// -------- final layer: normalize+ReLU of Hb fused with [1024]x[1024,2] dot
__global__ __launch_bounds__(256)
void k_final(const unsigned short* __restrict__ Hb,
             const float* __restrict__ sums, const float* __restrict__ sumsq,
             const float* __restrict__ g, const float* __restrict__ be,
             const float* __restrict__ W4, const float* __restrict__ b4,
             float* __restrict__ out) {
  const int t = threadIdx.x;
  const int w = t >> 6, lane = t & 63;
  const int row = blockIdx.x * 4 + w;
  const int kbase = lane * 16;
  const unsigned short* a = Hb + (size_t)row * HDIM + kbase;
  float s0 = 0.f, s1 = 0.f;
#pragma unroll
  for (int j = 0; j < 16; ++j) {
    const int col = kbase + j;
    const float mean = sums[col] * (1.f / N_CORES);
    const float var = sumsq[col] * (1.f / N_CORES) - mean * mean;
    const float sc = g[col] * rsqrtf(var + BN_EPS);
    const float sh = be[col] - mean * sc;
    const float av = fmaxf(bf2f(a[j]) * sc + sh, 0.f);
    s0 += av * W4[col * 2 + 0];
    s1 += av * W4[col * 2 + 1];
  }
#pragma unroll
  for (int off = 32; off >= 1; off >>= 1) {
    s0 += __shfl_down(s0, off, 64);
    s1 += __shfl_down(s1, off, 64);
  }
  if (lane == 0) {
    out[row * 2 + 0] = s0 + b4[0];
    out[row * 2 + 1] = s1 + b4[1];
  }
}

extern "C" void kernel_launch(void* const* d_in, const int* in_sizes, int n_in,
                              void* d_out, int out_size, void* d_ws, size_t ws_size,
                              hipStream_t stream) {
  (void)in_sizes; (void)n_in; (void)out_size; (void)ws_size;
  const float* x       = (const float*)d_in[0];
  const int* corelen   = (const int*)d_in[1];
  const float* W1  = (const float*)d_in[2];
  const float* b1  = (const float*)d_in[3];
  const float* g1  = (const float*)d_in[4];
  const float* be1 = (const float*)d_in[5];
  const float* W2  = (const float*)d_in[6];
  const float* b2  = (const float*)d_in[7];
  const float* g2  = (const float*)d_in[8];
  const float* be2 = (const float*)d_in[9];
  const float* W3  = (const float*)d_in[10];
  const float* b3  = (const float*)d_in[11];
  const float* g3  = (const float*)d_in[12];
  const float* be3 = (const float*)d_in[13];
  const float* W4  = (const float*)d_in[14];
  const float* b4  = (const float*)d_in[15];
  float* out = (float*)d_out;

  char* ws = (char*)d_ws;
  unsigned short* Hb   = (unsigned short*)(ws);               //  8 MB [4096,1024] bf16 (pre-BN)
  unsigned short* Abf  = (unsigned short*)(ws + (8u << 20));  //  8 MB [4096,1024] bf16 (activations)
  unsigned short* Wt   = (unsigned short*)(ws + (16u << 20)); //  6 MB 3x[1024,1024] bf16
  float* stats = (float*)(ws + (22u << 20));                  // 6*1024 f32 (per-layer sums/sumsq)

  // one fused prologue dispatch: segsum + 3 transposes + stats zero
  k_prep<<<N_CORES + 3 * 1024 + 1, 256, 0, stream>>>(
      x, corelen, Abf, W1, W2, W3, Wt, stats);

  const float* bs[3]  = {b1, b2, b3};
  const float* gs[3]  = {g1, g2, g3};
  const float* bes[3] = {be1, be2, be3};
  for (int l = 0; l < 3; ++l) {
    float* sums  = stats + l * 2 * HDIM;
    float* sumsq = sums + HDIM;
    k_gemm_bt<<<dim3(N_CORES / BM, HDIM / BN), 64, 0, stream>>>(
        Abf, Wt + (size_t)l * HDIM * HDIM, bs[l], Hb, sums, sumsq);
    if (l < 2)
      k_norm_relu<<<(N_CORES * HDIM / 8) / 256, 256, 0, stream>>>(
          Hb, sums, sumsq, gs[l], bes[l], Abf);
    else
      k_final<<<N_CORES / 4, 256, 0, stream>>>(
          Hb, sums, sumsq, gs[l], bes[l], W4, b4, out);
  }
}